// Round 13
// baseline (329.370 us; speedup 1.0000x reference)
//
#include <hip/hip_runtime.h>
#include <hip/hip_fp16.h>

#define SLOTS 64
#define DEGSTRIDE 16  // pad deg counters to 64B: kills same-line atomic serialization

typedef _Float16 half8 __attribute__((ext_vector_type(8)));
typedef float f32x4 __attribute__((ext_vector_type(4)));

// ---------- padded CSR build, 8-range XCD-filtered, SLOT-MAJOR ----------
// LOAD-BEARING (r9 A/B): single-scan de-filtered variant ran 123us vs 75us here.
// The 8x dst re-scan hits L3 (dst = 6.4MB); what it buys is atomics+stores
// confined to one XCD's L2 (bid&7 ~ XCD via round-robin dispatch).
__global__ __launch_bounds__(256) void fill_pad(const int* __restrict__ src,
                                                const int* __restrict__ dst, int E, int N,
                                                int* __restrict__ degp,
                                                int* __restrict__ colpad, int chunks) {
  int range = blockIdx.x & 7;
  int chunk = blockIdx.x >> 3;
  int per = (N + 7) >> 3;
  int lo = range * per, hi = min(N, lo + per);
  int e0 = (int)((long long)chunk * E / chunks);
  int e1 = (int)((long long)(chunk + 1) * E / chunks);
  for (int e = e0 + (int)threadIdx.x; e < e1; e += 256) {
    int d = dst[e];
    if (d >= lo && d < hi) {
      int p = atomicAdd(&degp[(size_t)d * DEGSTRIDE], 1);
      if (p < SLOTS) colpad[(size_t)p * N + d] = src[e];
    }
  }
}

// ---------- GEMM1 + dinv fold (r10-measured form) ----------
__global__ __launch_bounds__(256) void gemm_scale(const float* __restrict__ in,
                                                  const float* __restrict__ W,
                                                  const int* __restrict__ degp,
                                                  float* __restrict__ dinv,
                                                  int* __restrict__ degc,
                                                  __half* __restrict__ out, int N) {
  constexpr int K = 128;
  constexpr int LDK = K + 8;
  __shared__ __align__(16) _Float16 Wt[64][LDK];
  int t = threadIdx.x;
  int wave = t >> 6, lane = t & 63;
  int arow = lane & 15, kgrp = lane >> 4;
  constexpr int KK = K / 32;
  int row0 = blockIdx.x * 64;
  int row = row0 + wave * 16 + arow;

  // (1) issue A loads + output-row degs first (hide under W-stage)
  half8 af[KK];
  if (row < N) {
#pragma unroll
    for (int kk = 0; kk < KK; ++kk) {
      const float4* p = (const float4*)&in[(size_t)row * K + kk * 32 + kgrp * 8];
      float4 v0 = p[0], v1 = p[1];
      half8 h;
      h[0] = (_Float16)v0.x; h[1] = (_Float16)v0.y;
      h[2] = (_Float16)v0.z; h[3] = (_Float16)v0.w;
      h[4] = (_Float16)v1.x; h[5] = (_Float16)v1.y;
      h[6] = (_Float16)v1.z; h[7] = (_Float16)v1.w;
      af[kk] = h;
    }
  } else {
#pragma unroll
    for (int kk = 0; kk < KK; ++kk) af[kk] = (half8)((_Float16)0.f);
  }
  int rbase = row0 + wave * 16 + kgrp * 4;
  float dv[4];
#pragma unroll
  for (int r = 0; r < 4; ++r)
    dv[r] = (rbase + r < N)
        ? rsqrtf((float)(degp[(size_t)(rbase + r) * DEGSTRIDE] + 1))  // +1 self loop
        : 0.f;
  if (t < 64 && row0 + t < N) {
    int d = degp[(size_t)(row0 + t) * DEGSTRIDE];
    dinv[row0 + t] = rsqrtf((float)(d + 1));
    degc[row0 + t] = min(d, SLOTS);
  }

  // (2) stage W^T to LDS
  for (int j = t; j < K * 64; j += 256) {
    int k = j >> 6, c = j & 63;
    Wt[c][k] = (_Float16)W[j];
  }
  __syncthreads();

  // (3) MFMA: D frag col=l&15, row=(l>>4)*4+reg (harness-verified)
  f32x4 acc[4];
#pragma unroll
  for (int ct = 0; ct < 4; ++ct) acc[ct] = (f32x4)(0.f);
#pragma unroll
  for (int kk = 0; kk < KK; ++kk) {
#pragma unroll
    for (int ct = 0; ct < 4; ++ct) {
      half8 b = *(const half8*)&Wt[ct * 16 + arow][kk * 32 + kgrp * 8];
      acc[ct] = __builtin_amdgcn_mfma_f32_16x16x32_f16(af[kk], b, acc[ct], 0, 0, 0);
    }
  }

  // (4) epilogue: scale by dinv, store half
#pragma unroll
  for (int r = 0; r < 4; ++r) {
    int rr = rbase + r;
    if (rr < N) {
#pragma unroll
      for (int ct = 0; ct < 4; ++ct)
        out[(size_t)rr * 64 + ct * 16 + arow] = __float2half(acc[ct][r] * dv[r]);
    }
  }
}

// ---------- aggregation (r10-measured form, VERBATIM — inner loop is a sharp
// local optimum: r3/r6/r11/r12 all regressed it. DO NOT EDIT the gather loop.) ----
// one wave per contiguous node chunk; lane = feature column; lane l streams
// plane l (colpad[l*N+node]) sequentially -> cache-line reuse across nodes.
// mode 0 (layer 1): out[d] = dinv[d] * relu( dinv[d]*(g[d]+sum g[s]) + b1 )
//   (trailing dinv[d] = layer-2 prescale, folded free — W2 commuted to finalize)
// mode 1 (layer 2): pool-accumulate z[d] = dinv[d]*(y[d]+sum y[s]) (b2 in finalize)
__global__ __launch_bounds__(256) void aggregate(const __half* __restrict__ g,
                                                 const int* __restrict__ degc,
                                                 const int* __restrict__ colpad,
                                                 const float* __restrict__ dinv,
                                                 const float* __restrict__ bias,
                                                 const int* __restrict__ batch,
                                                 __half* __restrict__ out,
                                                 float* __restrict__ poolsum,
                                                 float* __restrict__ poolcnt,
                                                 int N, int mode) {
  int lane = threadIdx.x & 63;
  int wave = blockIdx.x * 4 + (threadIdx.x >> 6);
  int nwaves = gridDim.x * 4;
  int per = (N + nwaves - 1) / nwaves;
  int n0 = wave * per, n1 = min(N, n0 + per);
  if (n0 >= n1) return;
  float b = (mode == 0) ? bias[lane] : 0.f;
  int cur = mode ? batch[n0] : 0;
  float pacc = 0.f, pcnt = 0.f;
  const int* myplane = colpad + (size_t)lane * N;
  for (int node = n0; node < n1; ++node) {
    int deg = degc[node];
    int nb = (lane < deg) ? myplane[node] : 0;
    float a0 = __half2float(g[(size_t)node * 64 + lane]);  // self (dinv-prescaled)
    float a1 = 0.f, a2 = 0.f, a3 = 0.f;
    float a4 = 0.f, a5 = 0.f, a6 = 0.f, a7 = 0.f;
    int j = 0;
    for (; j + 7 < deg; j += 8) {  // 8 independent gathers in flight
      int s0 = __shfl(nb, j, 64);
      int s1 = __shfl(nb, j + 1, 64);
      int s2 = __shfl(nb, j + 2, 64);
      int s3 = __shfl(nb, j + 3, 64);
      int s4 = __shfl(nb, j + 4, 64);
      int s5 = __shfl(nb, j + 5, 64);
      int s6 = __shfl(nb, j + 6, 64);
      int s7 = __shfl(nb, j + 7, 64);
      a0 += __half2float(g[(size_t)s0 * 64 + lane]);
      a1 += __half2float(g[(size_t)s1 * 64 + lane]);
      a2 += __half2float(g[(size_t)s2 * 64 + lane]);
      a3 += __half2float(g[(size_t)s3 * 64 + lane]);
      a4 += __half2float(g[(size_t)s4 * 64 + lane]);
      a5 += __half2float(g[(size_t)s5 * 64 + lane]);
      a6 += __half2float(g[(size_t)s6 * 64 + lane]);
      a7 += __half2float(g[(size_t)s7 * 64 + lane]);
    }
    for (; j + 3 < deg; j += 4) {
      int s0 = __shfl(nb, j, 64);
      int s1 = __shfl(nb, j + 1, 64);
      int s2 = __shfl(nb, j + 2, 64);
      int s3 = __shfl(nb, j + 3, 64);
      a0 += __half2float(g[(size_t)s0 * 64 + lane]);
      a1 += __half2float(g[(size_t)s1 * 64 + lane]);
      a2 += __half2float(g[(size_t)s2 * 64 + lane]);
      a3 += __half2float(g[(size_t)s3 * 64 + lane]);
    }
    for (; j < deg; ++j) a0 += __half2float(g[(size_t)__shfl(nb, j, 64) * 64 + lane]);
    float dnode = dinv[node];
    float r = dnode * (((a0 + a1) + (a2 + a3)) + ((a4 + a5) + (a6 + a7))) + b;
    if (mode == 0) {
      out[(size_t)node * 64 + lane] = __float2half(dnode * fmaxf(r, 0.f));
    } else {
      int bg = batch[node];
      if (bg != cur) {
        atomicAdd(&poolsum[cur * 64 + lane], pacc);
        if (lane == 0) atomicAdd(&poolcnt[cur], pcnt);
        pacc = 0.f; pcnt = 0.f; cur = bg;
      }
      pacc += r; pcnt += 1.f;
    }
  }
  if (mode) {
    atomicAdd(&poolsum[cur * 64 + lane], pacc);
    if (lane == 0) atomicAdd(&poolcnt[cur], pcnt);
  }
}

// ---------- finalize: out[g] = (poolsum[g]/cnt) @ W2 + b2  (G x 64 x 64, fp32) ----------
__global__ __launch_bounds__(64) void finalize_gemm(const float* __restrict__ poolsum,
                                                    const float* __restrict__ poolcnt,
                                                    const float* __restrict__ W2,
                                                    const float* __restrict__ b2,
                                                    float* __restrict__ out, int Gn) {
  __shared__ float m[64];
  int g = blockIdx.x, c = threadIdx.x;
  float cnt = poolcnt[g];
  float inv = (cnt > 0.f) ? 1.f / cnt : 0.f;
  m[c] = poolsum[g * 64 + c] * inv;
  __syncthreads();
  float acc = 0.f;
#pragma unroll
  for (int k = 0; k < 64; ++k) acc = fmaf(m[k], W2[k * 64 + c], acc);
  out[g * 64 + c] = (cnt > 0.f) ? acc + b2[c] : 0.f;  // empty graph -> 0 (matches ref)
}

extern "C" void kernel_launch(void* const* d_in, const int* in_sizes, int n_in,
                              void* d_out, int out_size, void* d_ws, size_t ws_size,
                              hipStream_t stream) {
  const float* x   = (const float*)d_in[0];
  const int* ei    = (const int*)d_in[1];
  const int* batch = (const int*)d_in[2];
  const float* W1  = (const float*)d_in[3];
  const float* b1  = (const float*)d_in[4];
  const float* W2  = (const float*)d_in[5];
  const float* b2  = (const float*)d_in[6];
  float* out = (float*)d_out;

  int N  = in_sizes[2];
  int E  = in_sizes[1] / 2;
  int Gn = out_size / 64;

  char* ws = (char*)d_ws;
  size_t off = 0;
  auto alloc = [&](size_t bytes) -> void* {
    void* p = ws + off;
    off = (off + bytes + 255) & ~(size_t)255;
    return p;
  };
  float* poolsum = (float*)alloc(4ull * Gn * 64);
  float* poolcnt = (float*)alloc(4ull * Gn);
  size_t zero_bytes = off;  // zero-init region (pool accumulators)
  int* colpad    = (int*)alloc(4ull * (size_t)N * SLOTS);
  float* dinv    = (float*)alloc(4ull * N);
  int* degc      = (int*)alloc(4ull * N);
  __half* gbuf   = (__half*)alloc(2ull * (size_t)N * 64);
  __half* ybuf   = (__half*)alloc(2ull * (size_t)N * 64);
  // padded deg counters alias ybuf (disjoint lifetime: degp dead after gemm_scale,
  // ybuf first written by aggregate1)
  int* degp = (int*)ybuf;  // 4*DEGSTRIDE*N = 6.4MB <= 12.8MB ybuf
  (void)ws_size; (void)n_in;

  hipMemsetAsync(poolsum, 0, zero_bytes, stream);
  hipMemsetAsync(degp, 0, 4ull * (size_t)N * DEGSTRIDE, stream);

  const int* srcv = ei;
  const int* dstv = ei + E;
  int tiles64 = (N + 63) / 64;
  int chunks = 256;

  // CSR build: 8-range XCD-filtered (load-bearing, r9 A/B: 75us vs 123us)
  fill_pad<<<8 * chunks, 256, 0, stream>>>(srcv, dstv, E, N, degp, colpad, chunks);
  // GEMM1 + dinv fold
  gemm_scale<<<tiles64, 256, 0, stream>>>(x, W1, degp, dinv, degc, gbuf, N);

  // layer 1 aggregation -> ybuf = dinv * relu(.)  (layer-2 prescale folded in)
  // grid 4096 (was 2048 = exactly 8/CU): 2048 resident + 2048 queued gives
  // dynamic load balancing for deg-dependent per-wave runtimes (ONLY change vs r10)
  aggregate<<<4096, 256, 0, stream>>>(gbuf, degc, colpad, dinv, b1, batch, ybuf,
                                      nullptr, nullptr, N, 0);
  // layer 2 aggregation + mean-pool partials in z-space (W2 commuted to finalize)
  aggregate<<<4096, 256, 0, stream>>>(ybuf, degc, colpad, dinv, b1, batch, nullptr,
                                      poolsum, poolcnt, N, 1);
  // tiny fp32 GEMM tail: out = mean_z @ W2 + b2
  finalize_gemm<<<Gn, 64, 0, stream>>>(poolsum, poolcnt, W2, b2, out, Gn);
}

// Round 14
// 296.346 us; speedup vs baseline: 1.1114x; 1.1114x over previous
//
#include <hip/hip_runtime.h>
#include <hip/hip_fp16.h>

#define SLOTS 64
#define DEGSTRIDE 16  // pad deg counters to 64B: kills same-line atomic serialization

typedef _Float16 half8 __attribute__((ext_vector_type(8)));
typedef float f32x4 __attribute__((ext_vector_type(4)));

// ---------- padded CSR build, 8-range XCD-filtered, SLOT-MAJOR ----------
// LOAD-BEARING (r9 A/B): single-scan de-filtered variant ran 123us vs 75us here.
// The 8x dst re-scan hits L3 (dst = 6.4MB); what it buys is atomics+stores
// confined to one XCD's L2 (bid&7 ~ XCD via round-robin dispatch).
__global__ __launch_bounds__(256) void fill_pad(const int* __restrict__ src,
                                                const int* __restrict__ dst, int E, int N,
                                                int* __restrict__ degp,
                                                int* __restrict__ colpad, int chunks) {
  int range = blockIdx.x & 7;
  int chunk = blockIdx.x >> 3;
  int per = (N + 7) >> 3;
  int lo = range * per, hi = min(N, lo + per);
  int e0 = (int)((long long)chunk * E / chunks);
  int e1 = (int)((long long)(chunk + 1) * E / chunks);
  for (int e = e0 + (int)threadIdx.x; e < e1; e += 256) {
    int d = dst[e];
    if (d >= lo && d < hi) {
      int p = atomicAdd(&degp[(size_t)d * DEGSTRIDE], 1);
      if (p < SLOTS) colpad[(size_t)p * N + d] = src[e];
    }
  }
}

// ---------- GEMM1 + dinv fold (r10-measured form) ----------
__global__ __launch_bounds__(256) void gemm_scale(const float* __restrict__ in,
                                                  const float* __restrict__ W,
                                                  const int* __restrict__ degp,
                                                  float* __restrict__ dinv,
                                                  int* __restrict__ degc,
                                                  __half* __restrict__ out, int N) {
  constexpr int K = 128;
  constexpr int LDK = K + 8;
  __shared__ __align__(16) _Float16 Wt[64][LDK];
  int t = threadIdx.x;
  int wave = t >> 6, lane = t & 63;
  int arow = lane & 15, kgrp = lane >> 4;
  constexpr int KK = K / 32;
  int row0 = blockIdx.x * 64;
  int row = row0 + wave * 16 + arow;

  // (1) issue A loads + output-row degs first (hide under W-stage)
  half8 af[KK];
  if (row < N) {
#pragma unroll
    for (int kk = 0; kk < KK; ++kk) {
      const float4* p = (const float4*)&in[(size_t)row * K + kk * 32 + kgrp * 8];
      float4 v0 = p[0], v1 = p[1];
      half8 h;
      h[0] = (_Float16)v0.x; h[1] = (_Float16)v0.y;
      h[2] = (_Float16)v0.z; h[3] = (_Float16)v0.w;
      h[4] = (_Float16)v1.x; h[5] = (_Float16)v1.y;
      h[6] = (_Float16)v1.z; h[7] = (_Float16)v1.w;
      af[kk] = h;
    }
  } else {
#pragma unroll
    for (int kk = 0; kk < KK; ++kk) af[kk] = (half8)((_Float16)0.f);
  }
  int rbase = row0 + wave * 16 + kgrp * 4;
  float dv[4];
#pragma unroll
  for (int r = 0; r < 4; ++r)
    dv[r] = (rbase + r < N)
        ? rsqrtf((float)(degp[(size_t)(rbase + r) * DEGSTRIDE] + 1))  // +1 self loop
        : 0.f;
  if (t < 64 && row0 + t < N) {
    int d = degp[(size_t)(row0 + t) * DEGSTRIDE];
    dinv[row0 + t] = rsqrtf((float)(d + 1));
    degc[row0 + t] = min(d, SLOTS);
  }

  // (2) stage W^T to LDS
  for (int j = t; j < K * 64; j += 256) {
    int k = j >> 6, c = j & 63;
    Wt[c][k] = (_Float16)W[j];
  }
  __syncthreads();

  // (3) MFMA: D frag col=l&15, row=(l>>4)*4+reg (harness-verified)
  f32x4 acc[4];
#pragma unroll
  for (int ct = 0; ct < 4; ++ct) acc[ct] = (f32x4)(0.f);
#pragma unroll
  for (int kk = 0; kk < KK; ++kk) {
#pragma unroll
    for (int ct = 0; ct < 4; ++ct) {
      half8 b = *(const half8*)&Wt[ct * 16 + arow][kk * 32 + kgrp * 8];
      acc[ct] = __builtin_amdgcn_mfma_f32_16x16x32_f16(af[kk], b, acc[ct], 0, 0, 0);
    }
  }

  // (4) epilogue: scale by dinv, store half
#pragma unroll
  for (int r = 0; r < 4; ++r) {
    int rr = rbase + r;
    if (rr < N) {
#pragma unroll
      for (int ct = 0; ct < 4; ++ct)
        out[(size_t)rr * 64 + ct * 16 + arow] = __float2half(acc[ct][r] * dv[r]);
    }
  }
}

// ---------- aggregation (r10-measured form, VERBATIM — inner loop AND launch
// geometry are a sharp local optimum: r3/r6/r11/r12 regressed the loop, r13
// regressed the grid (4096 blocks broke plane-streaming line reuse). ----------
// one wave per contiguous node chunk (2048 blocks -> ~13 nodes/wave); lane =
// feature column; lane l streams plane l (colpad[l*N+node]) sequentially.
// mode 0 (layer 1): out[d] = dinv[d] * relu( dinv[d]*(g[d]+sum g[s]) + b1 )
//   (trailing dinv[d] = layer-2 prescale, folded free — W2 commuted to finalize)
// mode 1 (layer 2): pool-accumulate z[d] = dinv[d]*(y[d]+sum y[s]) (b2 in finalize)
__global__ __launch_bounds__(256) void aggregate(const __half* __restrict__ g,
                                                 const int* __restrict__ degc,
                                                 const int* __restrict__ colpad,
                                                 const float* __restrict__ dinv,
                                                 const float* __restrict__ bias,
                                                 const int* __restrict__ batch,
                                                 __half* __restrict__ out,
                                                 float* __restrict__ poolsum,
                                                 float* __restrict__ poolcnt,
                                                 int N, int mode) {
  int lane = threadIdx.x & 63;
  int wave = blockIdx.x * 4 + (threadIdx.x >> 6);
  int nwaves = gridDim.x * 4;
  int per = (N + nwaves - 1) / nwaves;
  int n0 = wave * per, n1 = min(N, n0 + per);
  if (n0 >= n1) return;
  float b = (mode == 0) ? bias[lane] : 0.f;
  int cur = mode ? batch[n0] : 0;
  float pacc = 0.f, pcnt = 0.f;
  const int* myplane = colpad + (size_t)lane * N;
  for (int node = n0; node < n1; ++node) {
    int deg = degc[node];
    int nb = (lane < deg) ? myplane[node] : 0;
    float a0 = __half2float(g[(size_t)node * 64 + lane]);  // self (dinv-prescaled)
    float a1 = 0.f, a2 = 0.f, a3 = 0.f;
    float a4 = 0.f, a5 = 0.f, a6 = 0.f, a7 = 0.f;
    int j = 0;
    for (; j + 7 < deg; j += 8) {  // 8 independent gathers in flight
      int s0 = __shfl(nb, j, 64);
      int s1 = __shfl(nb, j + 1, 64);
      int s2 = __shfl(nb, j + 2, 64);
      int s3 = __shfl(nb, j + 3, 64);
      int s4 = __shfl(nb, j + 4, 64);
      int s5 = __shfl(nb, j + 5, 64);
      int s6 = __shfl(nb, j + 6, 64);
      int s7 = __shfl(nb, j + 7, 64);
      a0 += __half2float(g[(size_t)s0 * 64 + lane]);
      a1 += __half2float(g[(size_t)s1 * 64 + lane]);
      a2 += __half2float(g[(size_t)s2 * 64 + lane]);
      a3 += __half2float(g[(size_t)s3 * 64 + lane]);
      a4 += __half2float(g[(size_t)s4 * 64 + lane]);
      a5 += __half2float(g[(size_t)s5 * 64 + lane]);
      a6 += __half2float(g[(size_t)s6 * 64 + lane]);
      a7 += __half2float(g[(size_t)s7 * 64 + lane]);
    }
    for (; j + 3 < deg; j += 4) {
      int s0 = __shfl(nb, j, 64);
      int s1 = __shfl(nb, j + 1, 64);
      int s2 = __shfl(nb, j + 2, 64);
      int s3 = __shfl(nb, j + 3, 64);
      a0 += __half2float(g[(size_t)s0 * 64 + lane]);
      a1 += __half2float(g[(size_t)s1 * 64 + lane]);
      a2 += __half2float(g[(size_t)s2 * 64 + lane]);
      a3 += __half2float(g[(size_t)s3 * 64 + lane]);
    }
    for (; j < deg; ++j) a0 += __half2float(g[(size_t)__shfl(nb, j, 64) * 64 + lane]);
    float dnode = dinv[node];
    float r = dnode * (((a0 + a1) + (a2 + a3)) + ((a4 + a5) + (a6 + a7))) + b;
    if (mode == 0) {
      out[(size_t)node * 64 + lane] = __float2half(dnode * fmaxf(r, 0.f));
    } else {
      int bg = batch[node];
      if (bg != cur) {
        atomicAdd(&poolsum[cur * 64 + lane], pacc);
        if (lane == 0) atomicAdd(&poolcnt[cur], pcnt);
        pacc = 0.f; pcnt = 0.f; cur = bg;
      }
      pacc += r; pcnt += 1.f;
    }
  }
  if (mode) {
    atomicAdd(&poolsum[cur * 64 + lane], pacc);
    if (lane == 0) atomicAdd(&poolcnt[cur], pcnt);
  }
}

// ---------- finalize: out[g] = (poolsum[g]/cnt) @ W2 + b2  (G x 64 x 64, fp32) ----------
__global__ __launch_bounds__(64) void finalize_gemm(const float* __restrict__ poolsum,
                                                    const float* __restrict__ poolcnt,
                                                    const float* __restrict__ W2,
                                                    const float* __restrict__ b2,
                                                    float* __restrict__ out, int Gn) {
  __shared__ float m[64];
  int g = blockIdx.x, c = threadIdx.x;
  float cnt = poolcnt[g];
  float inv = (cnt > 0.f) ? 1.f / cnt : 0.f;
  m[c] = poolsum[g * 64 + c] * inv;
  __syncthreads();
  float acc = 0.f;
#pragma unroll
  for (int k = 0; k < 64; ++k) acc = fmaf(m[k], W2[k * 64 + c], acc);
  out[g * 64 + c] = (cnt > 0.f) ? acc + b2[c] : 0.f;  // empty graph -> 0 (matches ref)
}

extern "C" void kernel_launch(void* const* d_in, const int* in_sizes, int n_in,
                              void* d_out, int out_size, void* d_ws, size_t ws_size,
                              hipStream_t stream) {
  const float* x   = (const float*)d_in[0];
  const int* ei    = (const int*)d_in[1];
  const int* batch = (const int*)d_in[2];
  const float* W1  = (const float*)d_in[3];
  const float* b1  = (const float*)d_in[4];
  const float* W2  = (const float*)d_in[5];
  const float* b2  = (const float*)d_in[6];
  float* out = (float*)d_out;

  int N  = in_sizes[2];
  int E  = in_sizes[1] / 2;
  int Gn = out_size / 64;

  char* ws = (char*)d_ws;
  size_t off = 0;
  auto alloc = [&](size_t bytes) -> void* {
    void* p = ws + off;
    off = (off + bytes + 255) & ~(size_t)255;
    return p;
  };
  float* poolsum = (float*)alloc(4ull * Gn * 64);
  float* poolcnt = (float*)alloc(4ull * Gn);
  size_t zero_bytes = off;  // zero-init region (pool accumulators)
  int* colpad    = (int*)alloc(4ull * (size_t)N * SLOTS);
  float* dinv    = (float*)alloc(4ull * N);
  int* degc      = (int*)alloc(4ull * N);
  __half* gbuf   = (__half*)alloc(2ull * (size_t)N * 64);
  __half* ybuf   = (__half*)alloc(2ull * (size_t)N * 64);
  // padded deg counters alias ybuf (disjoint lifetime: degp dead after gemm_scale,
  // ybuf first written by aggregate1)
  int* degp = (int*)ybuf;  // 4*DEGSTRIDE*N = 6.4MB <= 12.8MB ybuf
  (void)ws_size; (void)n_in;

  hipMemsetAsync(poolsum, 0, zero_bytes, stream);
  hipMemsetAsync(degp, 0, 4ull * (size_t)N * DEGSTRIDE, stream);

  const int* srcv = ei;
  const int* dstv = ei + E;
  int tiles64 = (N + 63) / 64;
  int chunks = 256;

  // CSR build: 8-range XCD-filtered (load-bearing, r9 A/B: 75us vs 123us)
  fill_pad<<<8 * chunks, 256, 0, stream>>>(srcv, dstv, E, N, degp, colpad, chunks);
  // GEMM1 + dinv fold
  gemm_scale<<<tiles64, 256, 0, stream>>>(x, W1, degp, dinv, degc, gbuf, N);

  // layer 1 aggregation -> ybuf = dinv * relu(.)  (layer-2 prescale folded in)
  aggregate<<<2048, 256, 0, stream>>>(gbuf, degc, colpad, dinv, b1, batch, ybuf,
                                      nullptr, nullptr, N, 0);
  // layer 2 aggregation + mean-pool partials in z-space (W2 commuted to finalize)
  aggregate<<<2048, 256, 0, stream>>>(ybuf, degc, colpad, dinv, b1, batch, nullptr,
                                      poolsum, poolcnt, N, 1);
  // tiny fp32 GEMM tail: out = mean_z @ W2 + b2
  finalize_gemm<<<Gn, 64, 0, stream>>>(poolsum, poolcnt, W2, b2, out, Gn);
}